// Round 6
// baseline (627.522 us; speedup 1.0000x reference)
//
#include <hip/hip_runtime.h>

// BiLSTM for MI355X (gfx950) — round 6.
//  K1 gpre_gemm (re-tiled): 4096 blocks x 256 rows; gpre[(b*256+t)][64] =
//     relu(x@W0+b0)@Wfx + bf' (split-bf16 MFMA, R4/R5-verified numerics), fp32 to d_ws.
//  K2 lstm_scan16: 256 blocks x 1 wave; 16 sequences per wave. Recurrent matvec as
//     mfma_f32_16x16x16f16: D[gate-tile][seq] = Wfh^T * H + gpre. C/D layout makes the
//     c/h update lane-local AND the new h is already in B-operand layout for the next
//     step -> zero cross-lane traffic in the serial loop. f16 hi+lo split (3-product).
//  Fallback: unchanged R4 fused kernel if ws_size < 268 MB.

typedef __attribute__((ext_vector_type(8))) short short8;
typedef __attribute__((ext_vector_type(4))) float floatx4;
typedef _Float16 half4 __attribute__((ext_vector_type(4)));

union F8 { uint32_t u[4]; short8 v; };

#define LDW 66  // LDS row stride (dwords): 66 mod 32 = 2 -> <=2-way bank aliasing (free)

__device__ __forceinline__ float tanh_fast(float x) {
    float e = __expf(-2.f * x);
    return __fdividef(2.f, 1.f + e) - 1.f;
}
__device__ __forceinline__ float sigf(float v) {
    float e = __expf(-v);
    return __fdividef(1.f, 1.f + e);
}

// split f[0..7] (fp32) into truncated-bf16 hi and residual-bf16 lo fragments (R4-verified)
__device__ __forceinline__ void split_pack(const float* f, uint32_t* hi, uint32_t* lo) {
#pragma unroll
    for (int i = 0; i < 4; ++i) {
        uint32_t u0 = __float_as_uint(f[2 * i]), u1 = __float_as_uint(f[2 * i + 1]);
        hi[i] = (u0 >> 16) | (u1 & 0xFFFF0000u);
        float r0 = f[2 * i]     - __uint_as_float(u0 & 0xFFFF0000u);
        float r1 = f[2 * i + 1] - __uint_as_float(u1 & 0xFFFF0000u);
        uint32_t v0 = __float_as_uint(r0), v1 = __float_as_uint(r1);
        lo[i] = (v0 >> 16) | (v1 & 0xFFFF0000u);
    }
}

// ===================== K1: gpre GEMM (256 rows/block) =====================
__global__ __launch_bounds__(256, 2)
void gpre_gemm(const float* __restrict__ x,
               const float* __restrict__ W0, const float* __restrict__ b0,
               const float* __restrict__ Wf, const float* __restrict__ bf,
               float* __restrict__ gpre)
{
    __shared__ __align__(16) float xtile[256 * 20 + 8];
    __shared__ __align__(16) float xh_t[4][16 * LDW];

    const int tid  = threadIdx.x;
    const int wv   = tid >> 6;
    const int j    = tid & 63;
    const int nl   = j & 15;
    const int quad = j >> 4;
    const int r0   = blockIdx.x * 256;

    // stage x[256][20] (1280 float4, coalesced)
    {
        const float4* src = (const float4*)(x + (size_t)r0 * 20);
        float4* dst = (float4*)xtile;
#pragma unroll
        for (int i = 0; i < 5; ++i) dst[tid + i * 256] = src[tid + i * 256];
    }
    __syncthreads();

    // B fragments (gathered once per block, used for 4 M-tiles per wave)
    F8 B1h[4], B1l[4];
#pragma unroll
    for (int T = 0; T < 4; ++T) {
        float w[8];
#pragma unroll
        for (int e = 0; e < 8; ++e) {
            int k = quad * 8 + e;
            w[e] = (k < 20) ? W0[k * 64 + T * 16 + nl] : 0.f;
        }
        split_pack(w, B1h[T].u, B1l[T].u);
    }
    F8 B2h[4][2], B2l[4][2];
#pragma unroll
    for (int T = 0; T < 4; ++T)
#pragma unroll
        for (int KH = 0; KH < 2; ++KH) {
            float w[8];
#pragma unroll
            for (int e = 0; e < 8; ++e) {
                int k = KH * 32 + quad * 8 + e;
                w[e] = Wf[k * 64 + T * 16 + nl];
            }
            split_pack(w, B2h[T][KH].u, B2l[T][KH].u);
        }

    float b0v[4], bfv[4];
#pragma unroll
    for (int T = 0; T < 4; ++T) {
        b0v[T] = b0[T * 16 + nl];
        bfv[T] = bf[T * 16 + nl] + ((T == 2) ? 1.f : 0.f);   // fold haiku forget +1
    }

#pragma unroll 1
    for (int tile = 0; tile < 4; ++tile) {
        const int lr = wv * 64 + tile * 16;   // local row base for this M-tile

        // A1 from LDS: xk[e] = x[lr+nl][quad*8+e], zero-padded k>=20
        float xk[8];
        if (quad < 2) {
            const float4* p = (const float4*)&xtile[(lr + nl) * 20 + quad * 8];
            float4 v0 = p[0], v1 = p[1];
            xk[0]=v0.x; xk[1]=v0.y; xk[2]=v0.z; xk[3]=v0.w;
            xk[4]=v1.x; xk[5]=v1.y; xk[6]=v1.z; xk[7]=v1.w;
        } else if (quad == 2) {
            const float4* p = (const float4*)&xtile[(lr + nl) * 20 + 16];
            float4 v0 = p[0];
            xk[0]=v0.x; xk[1]=v0.y; xk[2]=v0.z; xk[3]=v0.w;
            xk[4]=0.f; xk[5]=0.f; xk[6]=0.f; xk[7]=0.f;
        } else {
#pragma unroll
            for (int e = 0; e < 8; ++e) xk[e] = 0.f;
        }
        F8 A1h, A1l;
        split_pack(xk, A1h.u, A1l.u);

        floatx4 acc1[4];
#pragma unroll
        for (int T = 0; T < 4; ++T) acc1[T] = (floatx4){b0v[T], b0v[T], b0v[T], b0v[T]};
#pragma unroll
        for (int T = 0; T < 4; ++T) {
            acc1[T] = __builtin_amdgcn_mfma_f32_16x16x32_bf16(A1h.v, B1h[T].v, acc1[T], 0, 0, 0);
            acc1[T] = __builtin_amdgcn_mfma_f32_16x16x32_bf16(A1l.v, B1h[T].v, acc1[T], 0, 0, 0);
            acc1[T] = __builtin_amdgcn_mfma_f32_16x16x32_bf16(A1h.v, B1l[T].v, acc1[T], 0, 0, 0);
        }

        // relu + transpose via wave-private LDS
#pragma unroll
        for (int T = 0; T < 4; ++T)
#pragma unroll
            for (int reg = 0; reg < 4; ++reg)
                xh_t[wv][(quad * 4 + reg) * LDW + T * 16 + nl] = fmaxf(acc1[T][reg], 0.f);
        __builtin_amdgcn_wave_barrier();

        F8 A2h[2], A2l[2];
#pragma unroll
        for (int KH = 0; KH < 2; ++KH) {
            float xe[8];
#pragma unroll
            for (int e = 0; e < 8; ++e)
                xe[e] = xh_t[wv][nl * LDW + KH * 32 + quad * 8 + e];
            split_pack(xe, A2h[KH].u, A2l[KH].u);
        }

        floatx4 acc2[4];
#pragma unroll
        for (int T = 0; T < 4; ++T) acc2[T] = (floatx4){bfv[T], bfv[T], bfv[T], bfv[T]};
#pragma unroll
        for (int T = 0; T < 4; ++T)
#pragma unroll
            for (int KH = 0; KH < 2; ++KH) {
                acc2[T] = __builtin_amdgcn_mfma_f32_16x16x32_bf16(A2h[KH].v, B2h[T][KH].v, acc2[T], 0, 0, 0);
                acc2[T] = __builtin_amdgcn_mfma_f32_16x16x32_bf16(A2l[KH].v, B2h[T][KH].v, acc2[T], 0, 0, 0);
                acc2[T] = __builtin_amdgcn_mfma_f32_16x16x32_bf16(A2h[KH].v, B2l[T][KH].v, acc2[T], 0, 0, 0);
            }

        float* gp = gpre + (size_t)(r0 + lr) * 64;
#pragma unroll
        for (int T = 0; T < 4; ++T)
#pragma unroll
            for (int reg = 0; reg < 4; ++reg)
                gp[(quad * 4 + reg) * 64 + T * 16 + nl] = acc2[T][reg];
        __builtin_amdgcn_wave_barrier();
    }
}

// ===================== K2: 16-seq-per-wave MFMA scan =====================
// grid 256 x 64 threads. Wave w handles seqs [w*16, w*16+16).
// Lane (quad,nl): holds c/h for seq=nl, hid=quad*4+r (r=0..3).
__global__ __launch_bounds__(64, 1)
void lstm_scan16(const float* __restrict__ gpre,
                 const float* __restrict__ x,
                 const float* __restrict__ W0, const float* __restrict__ b0,
                 const float* __restrict__ Wf,
                 const float* __restrict__ Wb, const float* __restrict__ bb,
                 const float* __restrict__ W1, const float* __restrict__ b1,
                 const float* __restrict__ W2, const float* __restrict__ b2,
                 const float* __restrict__ W3, const float* __restrict__ b3,
                 float* __restrict__ out)
{
    __shared__ __align__(16) float hf[16 * 17];   // h_fwd[seq][hid] (pad 17)
    __shared__ __align__(16) float xh_sh[64];
    __shared__ __align__(16) float h_sh[48];      // [0:16) hf_q, [16:32) hb, [32:48) l2

    const int j    = threadIdx.x;
    const int nl   = j & 15;
    const int quad = j >> 4;
    const int s0   = blockIdx.x * 16;

    // A-frags: A_T[m=hid_out][k=hid_in] = Wfh[k][T*16+m]; lane m=nl, k=quad*4+e.
    half4 Ah[4], Al[4];
#pragma unroll
    for (int T = 0; T < 4; ++T) {
#pragma unroll
        for (int e = 0; e < 4; ++e) {
            float w = Wf[(64 + quad * 4 + e) * 64 + T * 16 + nl];
            _Float16 hi = (_Float16)w;
            Ah[T][e] = hi;
            Al[T][e] = (_Float16)(w - (float)hi);
        }
    }

    float c[4] = {0.f, 0.f, 0.f, 0.f};
    float h[4] = {0.f, 0.f, 0.f, 0.f};

    // gpre addressing: element [seq=s0+nl][t][gate=T*16+quad*4+r]
    const float* gp = gpre + ((size_t)(s0 + nl) * 256) * 64 + quad * 4;

    float4 pf[4][4];
#pragma unroll
    for (int slot = 0; slot < 4; ++slot)
#pragma unroll
        for (int T = 0; T < 4; ++T)
            pf[slot][T] = *(const float4*)(gp + slot * 64 + T * 16);

#pragma unroll 1
    for (int t = 0; t < 256; t += 4) {
#pragma unroll
        for (int slot = 0; slot < 4; ++slot) {
            // C init from prefetched gpre
            floatx4 d[4];
#pragma unroll
            for (int T = 0; T < 4; ++T)
                d[T] = (floatx4){pf[slot][T].x, pf[slot][T].y, pf[slot][T].z, pf[slot][T].w};

            // prefetch t+4+slot (depth 4)
            {
                int tn = t + 4 + slot; tn = (tn > 255) ? 255 : tn;
#pragma unroll
                for (int T = 0; T < 4; ++T)
                    pf[slot][T] = *(const float4*)(gp + tn * 64 + T * 16);
            }

            // B = h state, split f16 hi/lo (already in B-layout: k=quad*4+r, n=nl)
            half4 Bh, Bl;
#pragma unroll
            for (int r = 0; r < 4; ++r) {
                _Float16 hi = (_Float16)h[r];
                Bh[r] = hi;
                Bl[r] = (_Float16)(h[r] - (float)hi);
            }

            // D = Wfh^T * H + gpre  (3-product f16 split)
#pragma unroll
            for (int T = 0; T < 4; ++T) {
                d[T] = __builtin_amdgcn_mfma_f32_16x16x16f16(Ah[T], Bh, d[T], 0, 0, 0);
                d[T] = __builtin_amdgcn_mfma_f32_16x16x16f16(Al[T], Bh, d[T], 0, 0, 0);
                d[T] = __builtin_amdgcn_mfma_f32_16x16x16f16(Ah[T], Bl, d[T], 0, 0, 0);
            }

            // gates: tile 0=i, 1=g, 2=f (bias pre-folded), 3=o — all lane-local
#pragma unroll
            for (int r = 0; r < 4; ++r) {
                float gi = sigf(d[0][r]);
                float gg = tanh_fast(d[1][r]);
                float gf = sigf(d[2][r]);
                float go = sigf(d[3][r]);
                c[r] = fmaf(gf, c[r], gi * gg);
                h[r] = go * tanh_fast(c[r]);
            }
        }
    }

    // park h_fwd
#pragma unroll
    for (int r = 0; r < 4; ++r) hf[nl * 17 + quad * 4 + r] = h[r];
    __builtin_amdgcn_wave_barrier();

    const float gmul = (quad == 1) ? -2.f : -1.f;
    const float amul = (quad == 1) ? 2.f : 1.f;
    const float aadd = (quad == 1) ? -1.f : 0.f;

    // per-seq epilogue (16 iterations, one-time)
#pragma unroll 1
    for (int q = 0; q < 16; ++q) {
        const int s = s0 + q;

        // xh[255] recomputed exactly from x (lane-uniform -> scalar loads)
        {
            const float* xr = x + (size_t)s * (256 * 20) + 255 * 20;
            float sum = b0[j];
#pragma unroll
            for (int k = 0; k < 20; ++k) sum = fmaf(xr[k], W0[k * 64 + j], sum);
            xh_sh[j] = fmaxf(sum, 0.f);
            if (j < 16) h_sh[j] = hf[q * 17 + j];
        }
        __builtin_amdgcn_wave_barrier();

        // bwd LSTM single step from zero state (R5-verified)
        {
            float u0 = bb[j], u1 = 0.f, u2 = 0.f, u3 = 0.f;
            const float* xr = xh_sh;
#pragma unroll
            for (int k4 = 0; k4 < 16; ++k4) {
                u0 = fmaf(xr[4 * k4 + 0], Wb[(4 * k4 + 0) * 64 + j], u0);
                u1 = fmaf(xr[4 * k4 + 1], Wb[(4 * k4 + 1) * 64 + j], u1);
                u2 = fmaf(xr[4 * k4 + 2], Wb[(4 * k4 + 2) * 64 + j], u2);
                u3 = fmaf(xr[4 * k4 + 3], Wb[(4 * k4 + 3) * 64 + j], u3);
            }
            float gated = (u0 + u1) + (u2 + u3);
            float e = __expf(gmul * gated);
            float y = __fdividef(1.f, 1.f + e);
            float a = fmaf(y, amul, aadd);
            float ai = __shfl(a, nl, 64);
            float ag = __shfl(a, nl + 16, 64);
            float ao = __shfl(a, nl + 48, 64);
            float cb = ai * ag;
            float hb = ao * tanh_fast(cb);
            __builtin_amdgcn_wave_barrier();
            if (j < 16) h_sh[16 + j] = hb;
            __builtin_amdgcn_wave_barrier();
        }

        // head MLP (R5-verified)
        {
            float u0 = b1[j], u1 = 0.f, u2 = 0.f, u3 = 0.f;
            const float4* hs = (const float4*)h_sh;
#pragma unroll
            for (int k4 = 0; k4 < 8; ++k4) {
                float4 v = hs[k4];
                u0 = fmaf(v.x, W1[(4 * k4 + 0) * 64 + j], u0);
                u1 = fmaf(v.y, W1[(4 * k4 + 1) * 64 + j], u1);
                u2 = fmaf(v.z, W1[(4 * k4 + 2) * 64 + j], u2);
                u3 = fmaf(v.w, W1[(4 * k4 + 3) * 64 + j], u3);
            }
            float l1 = fmaxf((u0 + u1) + (u2 + u3), 0.f);
            __builtin_amdgcn_wave_barrier();
            xh_sh[j] = l1;
            __builtin_amdgcn_wave_barrier();

            if (j < 16) {
                float v0 = b2[j], v1 = 0.f, v2 = 0.f, v3 = 0.f;
                const float4* ls = (const float4*)xh_sh;
#pragma unroll
                for (int k4 = 0; k4 < 16; ++k4) {
                    float4 v = ls[k4];
                    v0 = fmaf(v.x, W2[(4 * k4 + 0) * 16 + j], v0);
                    v1 = fmaf(v.y, W2[(4 * k4 + 1) * 16 + j], v1);
                    v2 = fmaf(v.z, W2[(4 * k4 + 2) * 16 + j], v2);
                    v3 = fmaf(v.w, W2[(4 * k4 + 3) * 16 + j], v3);
                }
                h_sh[32 + j] = fmaxf((v0 + v1) + (v2 + v3), 0.f);
            }
            __builtin_amdgcn_wave_barrier();

            if (j < 2) {
                float o = b3[j];
#pragma unroll
                for (int k = 0; k < 16; ++k)
                    o = fmaf(h_sh[32 + k], W3[k * 2 + j], o);
                out[s * 2 + j] = o;
            }
            __builtin_amdgcn_wave_barrier();
        }
    }
}

// ===================== fallback: unchanged R4 fused kernel =====================
__global__ __launch_bounds__(64, 2)
void bilstm_fused_r4(const float* __restrict__ x,
                     const float* __restrict__ W0, const float* __restrict__ b0,
                     const float* __restrict__ Wf, const float* __restrict__ bf,
                     const float* __restrict__ Wb, const float* __restrict__ bb,
                     const float* __restrict__ W1, const float* __restrict__ b1,
                     const float* __restrict__ W2, const float* __restrict__ b2,
                     const float* __restrict__ W3, const float* __restrict__ b3,
                     float* __restrict__ out)
{
    __shared__ __align__(16) float lds_xh[16 * LDW];
    __shared__ __align__(16) float lds_g [16 * LDW];
    __shared__ __align__(16) float h_sh[48];

    const int j    = threadIdx.x;
    const int b    = blockIdx.x;
    const int nl   = j & 15;
    const int quad = j >> 4;

    int rot1 = __builtin_amdgcn_mov_dpp(j, 0x121, 0xf, 0xf, false);
    const bool plus = ((rot1 & 15) == ((nl + 1) & 15));

    float wfhp[16];
#pragma unroll
    for (int s = 0; s < 16; ++s) {
        const int srcq = plus ? ((nl + s) & 15) : ((nl + 16 - s) & 15);
        wfhp[s] = Wf[(64 + srcq) * 64 + j];
    }

    F8 B1h[4], B1l[4];
#pragma unroll
    for (int T = 0; T < 4; ++T) {
        float w[8];
#pragma unroll
        for (int e = 0; e < 8; ++e) {
            int k = quad * 8 + e;
            w[e] = (k < 20) ? W0[k * 64 + T * 16 + nl] : 0.f;
        }
        split_pack(w, B1h[T].u, B1l[T].u);
    }
    F8 B2h[4][2], B2l[4][2];
#pragma unroll
    for (int T = 0; T < 4; ++T)
#pragma unroll
        for (int KH = 0; KH < 2; ++KH) {
            float w[8];
#pragma unroll
            for (int e = 0; e < 8; ++e) {
                int k = KH * 32 + quad * 8 + e;
                w[e] = Wf[k * 64 + T * 16 + nl];
            }
            split_pack(w, B2h[T][KH].u, B2l[T][KH].u);
        }

    float b0v[4], bfv[4];
#pragma unroll
    for (int T = 0; T < 4; ++T) {
        b0v[T] = b0[T * 16 + nl];
        bfv[T] = bf[T * 16 + nl];
    }

    const float gmul  = (quad == 1) ? -2.f : -1.f;
    const float gbias = (quad == 2) ? 1.f : 0.f;
    const float amul  = (quad == 1) ? 2.f : 1.f;
    const float aadd  = (quad == 1) ? -1.f : 0.f;
    const bool  b0sel = (quad & 1) != 0;
    const bool  b1sel = (quad & 2) != 0;

    float c = 0.f, hh = 0.f;
    const float* xb = x + (size_t)b * (256 * 20);

#define ROT(v, S) __int_as_float(__builtin_amdgcn_mov_dpp(__float_as_int(v), 0x120 | (S), 0xf, 0xf, false))

#pragma unroll 1
    for (int ch = 0; ch < 16; ++ch) {
        const int t0 = ch * 16;
        const float* xrow = xb + (size_t)(t0 + nl) * 20;
        float xk[8];
#pragma unroll
        for (int e = 0; e < 8; ++e) {
            int k = quad * 8 + e;
            xk[e] = (k < 20) ? xrow[k] : 0.f;
        }
        F8 A1h, A1l;
        split_pack(xk, A1h.u, A1l.u);

        floatx4 acc1[4];
#pragma unroll
        for (int T = 0; T < 4; ++T) acc1[T] = (floatx4){b0v[T], b0v[T], b0v[T], b0v[T]};
#pragma unroll
        for (int T = 0; T < 4; ++T) {
            acc1[T] = __builtin_amdgcn_mfma_f32_16x16x32_bf16(A1h.v, B1h[T].v, acc1[T], 0, 0, 0);
            acc1[T] = __builtin_amdgcn_mfma_f32_16x16x32_bf16(A1l.v, B1h[T].v, acc1[T], 0, 0, 0);
            acc1[T] = __builtin_amdgcn_mfma_f32_16x16x32_bf16(A1h.v, B1l[T].v, acc1[T], 0, 0, 0);
        }
#pragma unroll
        for (int T = 0; T < 4; ++T)
#pragma unroll
            for (int reg = 0; reg < 4; ++reg)
                lds_xh[(quad * 4 + reg) * LDW + T * 16 + nl] = fmaxf(acc1[T][reg], 0.f);
        __builtin_amdgcn_wave_barrier();

        F8 A2h[2], A2l[2];
#pragma unroll
        for (int KH = 0; KH < 2; ++KH) {
            float xe[8];
#pragma unroll
            for (int e = 0; e < 8; ++e)
                xe[e] = lds_xh[nl * LDW + KH * 32 + quad * 8 + e];
            split_pack(xe, A2h[KH].u, A2l[KH].u);
        }

        floatx4 acc2[4];
#pragma unroll
        for (int T = 0; T < 4; ++T) acc2[T] = (floatx4){bfv[T], bfv[T], bfv[T], bfv[T]};
#pragma unroll
        for (int T = 0; T < 4; ++T)
#pragma unroll
            for (int KH = 0; KH < 2; ++KH) {
                acc2[T] = __builtin_amdgcn_mfma_f32_16x16x32_bf16(A2h[KH].v, B2h[T][KH].v, acc2[T], 0, 0, 0);
                acc2[T] = __builtin_amdgcn_mfma_f32_16x16x32_bf16(A2l[KH].v, B2h[T][KH].v, acc2[T], 0, 0, 0);
                acc2[T] = __builtin_amdgcn_mfma_f32_16x16x32_bf16(A2h[KH].v, B2l[T][KH].v, acc2[T], 0, 0, 0);
            }
#pragma unroll
        for (int T = 0; T < 4; ++T)
#pragma unroll
            for (int reg = 0; reg < 4; ++reg)
                lds_g[(quad * 4 + reg) * LDW + T * 16 + nl] = acc2[T][reg];
        __builtin_amdgcn_wave_barrier();

        float gcur = lds_g[j];
#pragma unroll
        for (int tau = 0; tau < 16; ++tau) {
            float gnext = lds_g[((tau < 15) ? (tau + 1) : 15) * LDW + j];
            float v0 = hh * wfhp[0];
            float v1 = ROT(hh, 1) * wfhp[1];
            float v2 = ROT(hh, 2) * wfhp[2];
            float v3 = ROT(hh, 3) * wfhp[3];
            v0 = fmaf(ROT(hh, 4),  wfhp[4],  v0);
            v1 = fmaf(ROT(hh, 5),  wfhp[5],  v1);
            v2 = fmaf(ROT(hh, 6),  wfhp[6],  v2);
            v3 = fmaf(ROT(hh, 7),  wfhp[7],  v3);
            v0 = fmaf(ROT(hh, 8),  wfhp[8],  v0);
            v1 = fmaf(ROT(hh, 9),  wfhp[9],  v1);
            v2 = fmaf(ROT(hh, 10), wfhp[10], v2);
            v3 = fmaf(ROT(hh, 11), wfhp[11], v3);
            v0 = fmaf(ROT(hh, 12), wfhp[12], v0);
            v1 = fmaf(ROT(hh, 13), wfhp[13], v1);
            v2 = fmaf(ROT(hh, 14), wfhp[14], v2);
            v3 = fmaf(ROT(hh, 15), wfhp[15], v3);
            float gated = gcur + ((v0 + v1) + (v2 + v3));

            float e = __expf(gmul * (gated + gbias));
            float y = __fdividef(1.f, 1.f + e);
            float a = fmaf(y, amul, aadd);

            float d1 = __shfl_xor(a, 16);
            float d2 = __shfl_xor(a, 32);
            float d3 = __shfl_xor(a, 48);
            float lo  = b0sel ? d1 : a;
            float hi  = b0sel ? d3 : d2;
            float lo1 = b0sel ? a  : d1;
            float hi1 = b0sel ? d2 : d3;
            float ai = b1sel ? hi  : lo;
            float ag = b1sel ? hi1 : lo1;
            float af = b1sel ? lo  : hi;
            float ao = b1sel ? lo1 : hi1;

            c  = fmaf(af, c, ai * ag);
            hh = ao * tanh_fast(c);
            gcur = gnext;
        }
    }

    if (j < 16) h_sh[j] = hh;
    __builtin_amdgcn_wave_barrier();

    {
        float u0 = bb[j], u1 = 0.f, u2 = 0.f, u3 = 0.f;
        const float* xr = &lds_xh[15 * LDW];
#pragma unroll
        for (int k4 = 0; k4 < 16; ++k4) {
            u0 = fmaf(xr[4 * k4 + 0], Wb[(4 * k4 + 0) * 64 + j], u0);
            u1 = fmaf(xr[4 * k4 + 1], Wb[(4 * k4 + 1) * 64 + j], u1);
            u2 = fmaf(xr[4 * k4 + 2], Wb[(4 * k4 + 2) * 64 + j], u2);
            u3 = fmaf(xr[4 * k4 + 3], Wb[(4 * k4 + 3) * 64 + j], u3);
        }
        float gated = (u0 + u1) + (u2 + u3);
        float e = __expf(gmul * gated);
        float y = __fdividef(1.f, 1.f + e);
        float a = fmaf(y, amul, aadd);
        float ai = __shfl(a, nl, 64);
        float ag = __shfl(a, nl + 16, 64);
        float ao = __shfl(a, nl + 48, 64);
        float cb = ai * ag;
        float hb = ao * tanh_fast(cb);
        __builtin_amdgcn_wave_barrier();
        if (j < 16) h_sh[16 + j] = hb;
        __builtin_amdgcn_wave_barrier();
    }

    {
        float u0 = b1[j], u1 = 0.f, u2 = 0.f, u3 = 0.f;
        const float4* hs = (const float4*)h_sh;
#pragma unroll
        for (int k4 = 0; k4 < 8; ++k4) {
            float4 v = hs[k4];
            u0 = fmaf(v.x, W1[(4 * k4 + 0) * 64 + j], u0);
            u1 = fmaf(v.y, W1[(4 * k4 + 1) * 64 + j], u1);
            u2 = fmaf(v.z, W1[(4 * k4 + 2) * 64 + j], u2);
            u3 = fmaf(v.w, W1[(4 * k4 + 3) * 64 + j], u3);
        }
        float l1 = fmaxf((u0 + u1) + (u2 + u3), 0.f);
        __builtin_amdgcn_wave_barrier();
        lds_g[j] = l1;
        __builtin_amdgcn_wave_barrier();

        if (j < 16) {
            float v0 = b2[j], v1 = 0.f, v2 = 0.f, v3 = 0.f;
            const float4* ls = (const float4*)lds_g;
#pragma unroll
            for (int k4 = 0; k4 < 16; ++k4) {
                float4 v = ls[k4];
                v0 = fmaf(v.x, W2[(4 * k4 + 0) * 16 + j], v0);
                v1 = fmaf(v.y, W2[(4 * k4 + 1) * 16 + j], v1);
                v2 = fmaf(v.z, W2[(4 * k4 + 2) * 16 + j], v2);
                v3 = fmaf(v.w, W2[(4 * k4 + 3) * 16 + j], v3);
            }
            h_sh[32 + j] = fmaxf((v0 + v1) + (v2 + v3), 0.f);
        }
        __builtin_amdgcn_wave_barrier();

        if (j < 2) {
            float o = b3[j];
#pragma unroll
            for (int k = 0; k < 16; ++k)
                o = fmaf(h_sh[32 + k], W3[k * 2 + j], o);
            out[b * 2 + j] = o;
        }
    }
}

extern "C" void kernel_launch(void* const* d_in, const int* in_sizes, int n_in,
                              void* d_out, int out_size, void* d_ws, size_t ws_size,
                              hipStream_t stream) {
    const float* x  = (const float*)d_in[0];
    const float* W0 = (const float*)d_in[1];
    const float* b0 = (const float*)d_in[2];
    const float* Wf = (const float*)d_in[3];
    const float* bf = (const float*)d_in[4];
    const float* Wb = (const float*)d_in[5];
    const float* bb = (const float*)d_in[6];
    const float* W1 = (const float*)d_in[7];
    const float* b1 = (const float*)d_in[8];
    const float* W2 = (const float*)d_in[9];
    const float* b2 = (const float*)d_in[10];
    const float* W3 = (const float*)d_in[11];
    const float* b3 = (const float*)d_in[12];
    float* outp = (float*)d_out;

    const size_t need = (size_t)4096 * 256 * 64 * sizeof(float);  // 268 MB
    if (ws_size >= need) {
        float* gpre = (float*)d_ws;
        hipLaunchKernelGGL(gpre_gemm, dim3(4096), dim3(256), 0, stream,
                           x, W0, b0, Wf, bf, gpre);
        hipLaunchKernelGGL(lstm_scan16, dim3(256), dim3(64), 0, stream,
                           gpre, x, W0, b0, Wf, Wb, bb, W1, b1, W2, b2, W3, b3, outp);
    } else {
        hipLaunchKernelGGL(bilstm_fused_r4, dim3(4096), dim3(64), 0, stream,
                           x, W0, b0, Wf, bf, Wb, bb, W1, b1, W2, b2, W3, b3, outp);
    }
}

// Round 7
// 357.711 us; speedup vs baseline: 1.7543x; 1.7543x over previous
//
#include <hip/hip_runtime.h>

// BiLSTM for MI355X (gfx950) — round 7.
//  K1 gpre_gemm (rewritten): 1024 blocks x 256 thr; each wave streams 16 tiles
//     (256 rows) of gpre[(b*256+t)][64] = relu(x@W0+b0)@Wfx + bf' (split-bf16 MFMA,
//     R4..R6-verified numerics). No block staging / no __syncthreads; x loaded
//     per-lane with 1-tile register prefetch; gpre routed through a wave-private
//     LDS transpose so stores are fully coalesced 1KB dwordx4.
//  K2 lstm_scan: verbatim R5 (163 us proven): 1 seq/wave, DPP row_ror h-matvec,
//     depth-8 gpre prefetch, butterfly gate gather, fused epilogue.
//  Fallback: R4 fused kernel if ws_size < 268 MB.

typedef __attribute__((ext_vector_type(8))) short short8;
typedef __attribute__((ext_vector_type(4))) float floatx4;

union F8 { uint32_t u[4]; short8 v; };

#define LDW  66  // fallback-kernel LDS stride (R4 layout, unchanged)
#define LDW2 68  // K1 stride: keeps all b128 LDS accesses 16B-aligned; 68%32=4

__device__ __forceinline__ float tanh_fast(float x) {
    float e = __expf(-2.f * x);
    return __fdividef(2.f, 1.f + e) - 1.f;
}

// rotate v right by S within each row of 16 lanes (DPP row_ror:S)
#define ROT(v, S) __int_as_float(__builtin_amdgcn_mov_dpp(__float_as_int(v), 0x120 | (S), 0xf, 0xf, false))

// split f[0..7] (fp32) into truncated-bf16 hi and residual-bf16 lo fragments (R4-verified)
__device__ __forceinline__ void split_pack(const float* f, uint32_t* hi, uint32_t* lo) {
#pragma unroll
    for (int i = 0; i < 4; ++i) {
        uint32_t u0 = __float_as_uint(f[2 * i]), u1 = __float_as_uint(f[2 * i + 1]);
        hi[i] = (u0 >> 16) | (u1 & 0xFFFF0000u);
        float r0 = f[2 * i]     - __uint_as_float(u0 & 0xFFFF0000u);
        float r1 = f[2 * i + 1] - __uint_as_float(u1 & 0xFFFF0000u);
        uint32_t v0 = __float_as_uint(r0), v1 = __float_as_uint(r1);
        lo[i] = (v0 >> 16) | (v1 & 0xFFFF0000u);
    }
}

// ===================== K1: streaming gpre GEMM =====================
// grid 1024 x 256. wave_id = blockIdx*4+wv handles rows [wave_id*256, +256) in 16 tiles.
__global__ __launch_bounds__(256, 2)
void gpre_gemm(const float* __restrict__ x,
               const float* __restrict__ W0, const float* __restrict__ b0,
               const float* __restrict__ Wf, const float* __restrict__ bf,
               float* __restrict__ gpre)
{
    __shared__ __align__(16) float tA[4][16 * LDW2];  // xh transpose (wave-private)
    __shared__ __align__(16) float tB[4][16 * LDW2];  // gpre transpose (wave-private)

    const int tid  = threadIdx.x;
    const int wv   = tid >> 6;
    const int j    = tid & 63;
    const int nl   = j & 15;
    const int quad = j >> 4;

    // ---- B fragments (gathered once, used for 16 tiles)
    F8 B1h[4], B1l[4];
#pragma unroll
    for (int T = 0; T < 4; ++T) {
        float w[8];
#pragma unroll
        for (int e = 0; e < 8; ++e) {
            int k = quad * 8 + e;
            w[e] = (k < 20) ? W0[k * 64 + T * 16 + nl] : 0.f;
        }
        split_pack(w, B1h[T].u, B1l[T].u);
    }
    F8 B2h[4][2], B2l[4][2];
#pragma unroll
    for (int T = 0; T < 4; ++T)
#pragma unroll
        for (int KH = 0; KH < 2; ++KH) {
            float w[8];
#pragma unroll
            for (int e = 0; e < 8; ++e) {
                int k = KH * 32 + quad * 8 + e;
                w[e] = Wf[k * 64 + T * 16 + nl];
            }
            split_pack(w, B2h[T][KH].u, B2l[T][KH].u);
        }

    float b0v[4], bfv[4];
#pragma unroll
    for (int T = 0; T < 4; ++T) {
        b0v[T] = b0[T * 16 + nl];
        bfv[T] = bf[T * 16 + nl] + ((T == 2) ? 1.f : 0.f);   // fold haiku forget +1
    }

    const size_t base = (size_t)(blockIdx.x * 4 + wv) * 256;

    // ---- x prefetch (1 tile deep). Lane (quad,nl) needs x[r+nl][quad*8 .. +7].
    float4 xp0, xp1;
    {
        const float* xr = x + (base + nl) * 20;
        if (quad < 2) {
            xp0 = *(const float4*)(xr + quad * 8);
            xp1 = *(const float4*)(xr + quad * 8 + 4);
        } else if (quad == 2) {
            xp0 = *(const float4*)(xr + 16);
            xp1 = (float4){0.f, 0.f, 0.f, 0.f};
        } else {
            xp0 = (float4){0.f, 0.f, 0.f, 0.f};
            xp1 = (float4){0.f, 0.f, 0.f, 0.f};
        }
    }

#pragma unroll 1
    for (int tile = 0; tile < 16; ++tile) {
        const size_t r = base + tile * 16;

        float xk[8] = {xp0.x, xp0.y, xp0.z, xp0.w, xp1.x, xp1.y, xp1.z, xp1.w};

        // prefetch next tile's x
        {
            int tn = (tile < 15) ? (tile + 1) : 15;
            const float* xr = x + (base + tn * 16 + nl) * 20;
            if (quad < 2) {
                xp0 = *(const float4*)(xr + quad * 8);
                xp1 = *(const float4*)(xr + quad * 8 + 4);
            } else if (quad == 2) {
                xp0 = *(const float4*)(xr + 16);
            }
        }

        F8 A1h, A1l;
        split_pack(xk, A1h.u, A1l.u);

        floatx4 acc1[4];
#pragma unroll
        for (int T = 0; T < 4; ++T) acc1[T] = (floatx4){b0v[T], b0v[T], b0v[T], b0v[T]};
#pragma unroll
        for (int T = 0; T < 4; ++T) {
            acc1[T] = __builtin_amdgcn_mfma_f32_16x16x32_bf16(A1h.v, B1h[T].v, acc1[T], 0, 0, 0);
            acc1[T] = __builtin_amdgcn_mfma_f32_16x16x32_bf16(A1l.v, B1h[T].v, acc1[T], 0, 0, 0);
            acc1[T] = __builtin_amdgcn_mfma_f32_16x16x32_bf16(A1h.v, B1l[T].v, acc1[T], 0, 0, 0);
        }

        // relu + transpose (C-layout -> [tau][e])
#pragma unroll
        for (int T = 0; T < 4; ++T)
#pragma unroll
            for (int reg = 0; reg < 4; ++reg)
                tA[wv][(quad * 4 + reg) * LDW2 + T * 16 + nl] = fmaxf(acc1[T][reg], 0.f);
        __builtin_amdgcn_wave_barrier();

        F8 A2h[2], A2l[2];
#pragma unroll
        for (int KH = 0; KH < 2; ++KH) {
            float xe[8];
#pragma unroll
            for (int e = 0; e < 8; ++e)
                xe[e] = tA[wv][nl * LDW2 + KH * 32 + quad * 8 + e];
            split_pack(xe, A2h[KH].u, A2l[KH].u);
        }

        floatx4 acc2[4];
#pragma unroll
        for (int T = 0; T < 4; ++T) acc2[T] = (floatx4){bfv[T], bfv[T], bfv[T], bfv[T]};
#pragma unroll
        for (int T = 0; T < 4; ++T)
#pragma unroll
            for (int KH = 0; KH < 2; ++KH) {
                acc2[T] = __builtin_amdgcn_mfma_f32_16x16x32_bf16(A2h[KH].v, B2h[T][KH].v, acc2[T], 0, 0, 0);
                acc2[T] = __builtin_amdgcn_mfma_f32_16x16x32_bf16(A2l[KH].v, B2h[T][KH].v, acc2[T], 0, 0, 0);
                acc2[T] = __builtin_amdgcn_mfma_f32_16x16x32_bf16(A2h[KH].v, B2l[T][KH].v, acc2[T], 0, 0, 0);
            }

        // gpre transpose -> coalesced 1KB stores
#pragma unroll
        for (int T = 0; T < 4; ++T)
#pragma unroll
            for (int reg = 0; reg < 4; ++reg)
                tB[wv][(quad * 4 + reg) * LDW2 + T * 16 + nl] = acc2[T][reg];
        __builtin_amdgcn_wave_barrier();

        float* gp = gpre + r * 64;
#pragma unroll
        for (int p = 0; p < 4; ++p) {
            float4 v = *(const float4*)&tB[wv][(p * 4 + quad) * LDW2 + 4 * nl];
            *(float4*)(gp + p * 256 + j * 4) = v;
        }
        __builtin_amdgcn_wave_barrier();   // protect tA/tB reuse next tile
    }
}

// ===================== K2: serial scan + epilogue (verbatim R5, 163us proven) ==========
__global__ __launch_bounds__(256, 4)
void lstm_scan(const float* __restrict__ gpre,
               const float* __restrict__ x,
               const float* __restrict__ W0, const float* __restrict__ b0,
               const float* __restrict__ Wf,
               const float* __restrict__ Wb, const float* __restrict__ bb,
               const float* __restrict__ W1, const float* __restrict__ b1,
               const float* __restrict__ W2, const float* __restrict__ b2,
               const float* __restrict__ W3, const float* __restrict__ b3,
               float* __restrict__ out)
{
    __shared__ __align__(16) float xh_sh[4][64];
    __shared__ __align__(16) float h_sh[4][48];   // [0:16) hf, [16:32) hb, [32:48) l2

    const int wv   = threadIdx.x >> 6;
    const int j    = threadIdx.x & 63;
    const int b    = blockIdx.x * 4 + wv;
    const int nl   = j & 15;
    const int quad = j >> 4;

    int rot1 = __builtin_amdgcn_mov_dpp(j, 0x121, 0xf, 0xf, false);
    const bool plus = ((rot1 & 15) == ((nl + 1) & 15));

    float wfhp[16];
#pragma unroll
    for (int s = 0; s < 16; ++s) {
        const int srcq = plus ? ((nl + s) & 15) : ((nl + 16 - s) & 15);
        wfhp[s] = Wf[(64 + srcq) * 64 + j];
    }

    const float gmul  = (quad == 1) ? -2.f : -1.f;   // f-gate +1 folded in gpre
    const float amul  = (quad == 1) ? 2.f : 1.f;
    const float aadd  = (quad == 1) ? -1.f : 0.f;
    const bool  b0sel = (quad & 1) != 0;
    const bool  b1sel = (quad & 2) != 0;

    float c = 0.f, hh = 0.f;
    const float* gb = gpre + (size_t)b * (256 * 64);

    float gbuf[8];
#pragma unroll
    for (int i = 0; i < 8; ++i) gbuf[i] = gb[i * 64 + j];

#pragma unroll 1
    for (int t = 0; t < 256; t += 8) {
#pragma unroll
        for (int i = 0; i < 8; ++i) {
            float gated0 = gbuf[i];
            {
                int tf = t + 8 + i; tf = (tf > 255) ? 255 : tf;
                gbuf[i] = gb[tf * 64 + j];
            }
            float v0 = hh * wfhp[0];
            float v1 = ROT(hh, 1) * wfhp[1];
            float v2 = ROT(hh, 2) * wfhp[2];
            float v3 = ROT(hh, 3) * wfhp[3];
            v0 = fmaf(ROT(hh, 4),  wfhp[4],  v0);
            v1 = fmaf(ROT(hh, 5),  wfhp[5],  v1);
            v2 = fmaf(ROT(hh, 6),  wfhp[6],  v2);
            v3 = fmaf(ROT(hh, 7),  wfhp[7],  v3);
            v0 = fmaf(ROT(hh, 8),  wfhp[8],  v0);
            v1 = fmaf(ROT(hh, 9),  wfhp[9],  v1);
            v2 = fmaf(ROT(hh, 10), wfhp[10], v2);
            v3 = fmaf(ROT(hh, 11), wfhp[11], v3);
            v0 = fmaf(ROT(hh, 12), wfhp[12], v0);
            v1 = fmaf(ROT(hh, 13), wfhp[13], v1);
            v2 = fmaf(ROT(hh, 14), wfhp[14], v2);
            v3 = fmaf(ROT(hh, 15), wfhp[15], v3);
            float gated = gated0 + ((v0 + v1) + (v2 + v3));

            float e = __expf(gmul * gated);
            float y = __fdividef(1.f, 1.f + e);
            float a = fmaf(y, amul, aadd);

            float d1 = __shfl_xor(a, 16);
            float d2 = __shfl_xor(a, 32);
            float d3 = __shfl_xor(a, 48);
            float lo  = b0sel ? d1 : a;
            float hi  = b0sel ? d3 : d2;
            float lo1 = b0sel ? a  : d1;
            float hi1 = b0sel ? d2 : d3;
            float ai = b1sel ? hi  : lo;
            float ag = b1sel ? hi1 : lo1;
            float af = b1sel ? lo  : hi;
            float ao = b1sel ? lo1 : hi1;

            c  = fmaf(af, c, ai * ag);
            hh = ao * tanh_fast(c);
        }
    }

    // epilogue: recompute xh[255] exactly from x
    {
        const float* xr = x + (size_t)b * (256 * 20) + 255 * 20;
        float s = b0[j];
#pragma unroll
        for (int k = 0; k < 20; ++k) s = fmaf(xr[k], W0[k * 64 + j], s);
        xh_sh[wv][j] = fmaxf(s, 0.f);
        if (j < 16) h_sh[wv][j] = hh;
    }
    __builtin_amdgcn_wave_barrier();

    // bwd LSTM single step from zero state
    {
        float u0 = bb[j], u1 = 0.f, u2 = 0.f, u3 = 0.f;
        const float* xr = xh_sh[wv];
#pragma unroll
        for (int k4 = 0; k4 < 16; ++k4) {
            u0 = fmaf(xr[4 * k4 + 0], Wb[(4 * k4 + 0) * 64 + j], u0);
            u1 = fmaf(xr[4 * k4 + 1], Wb[(4 * k4 + 1) * 64 + j], u1);
            u2 = fmaf(xr[4 * k4 + 2], Wb[(4 * k4 + 2) * 64 + j], u2);
            u3 = fmaf(xr[4 * k4 + 3], Wb[(4 * k4 + 3) * 64 + j], u3);
        }
        float gated = (u0 + u1) + (u2 + u3);
        float e = __expf(gmul * gated);
        float y = __fdividef(1.f, 1.f + e);
        float a = fmaf(y, amul, aadd);
        float ai = __shfl(a, nl, 64);
        float ag = __shfl(a, nl + 16, 64);
        float ao = __shfl(a, nl + 48, 64);
        float cb = ai * ag;
        float hb = ao * tanh_fast(cb);
        __builtin_amdgcn_wave_barrier();
        if (j < 16) h_sh[wv][16 + j] = hb;
        __builtin_amdgcn_wave_barrier();
    }

    // head MLP
    {
        float u0 = b1[j], u1 = 0.f, u2 = 0.f, u3 = 0.f;
        const float4* hs = (const float4*)h_sh[wv];
#pragma unroll
        for (int k4 = 0; k4 < 8; ++k4) {
            float4 v = hs[k4];
            u0 = fmaf(v.x, W1[(4 * k4 + 0) * 64 + j], u0);
            u1 = fmaf(v.y, W1[(4 * k4 + 1) * 64 + j], u1);
            u2 = fmaf(v.z, W1[(4 * k4 + 2) * 64 + j], u2);
            u3 = fmaf(v.w, W1[(4 * k4 + 3) * 64 + j], u3);
        }
        float l1 = fmaxf((u0 + u1) + (u2 + u3), 0.f);
        __builtin_amdgcn_wave_barrier();
        xh_sh[wv][j] = l1;
        __builtin_amdgcn_wave_barrier();

        if (j < 16) {
            float v0 = b2[j], v1 = 0.f, v2 = 0.f, v3 = 0.f;
            const float4* ls = (const float4*)xh_sh[wv];
#pragma unroll
            for (int k4 = 0; k4 < 16; ++k4) {
                float4 v = ls[k4];
                v0 = fmaf(v.x, W2[(4 * k4 + 0) * 16 + j], v0);
                v1 = fmaf(v.y, W2[(4 * k4 + 1) * 16 + j], v1);
                v2 = fmaf(v.z, W2[(4 * k4 + 2) * 16 + j], v2);
                v3 = fmaf(v.w, W2[(4 * k4 + 3) * 16 + j], v3);
            }
            h_sh[wv][32 + j] = fmaxf((v0 + v1) + (v2 + v3), 0.f);
        }
        __builtin_amdgcn_wave_barrier();

        if (j < 2) {
            float o = b3[j];
#pragma unroll
            for (int k = 0; k < 16; ++k)
                o = fmaf(h_sh[wv][32 + k], W3[k * 2 + j], o);
            out[b * 2 + j] = o;
        }
    }
}

// ===================== fallback: unchanged R4 fused kernel =====================
__global__ __launch_bounds__(64, 2)
void bilstm_fused_r4(const float* __restrict__ x,
                     const float* __restrict__ W0, const float* __restrict__ b0,
                     const float* __restrict__ Wf, const float* __restrict__ bf,
                     const float* __restrict__ Wb, const float* __restrict__ bb,
                     const float* __restrict__ W1, const float* __restrict__ b1,
                     const float* __restrict__ W2, const float* __restrict__ b2,
                     const float* __restrict__ W3, const float* __restrict__ b3,
                     float* __restrict__ out)
{
    __shared__ __align__(16) float lds_xh[16 * LDW];
    __shared__ __align__(16) float lds_g [16 * LDW];
    __shared__ __align__(16) float h_sh[48];

    const int j    = threadIdx.x;
    const int b    = blockIdx.x;
    const int nl   = j & 15;
    const int quad = j >> 4;

    int rot1 = __builtin_amdgcn_mov_dpp(j, 0x121, 0xf, 0xf, false);
    const bool plus = ((rot1 & 15) == ((nl + 1) & 15));

    float wfhp[16];
#pragma unroll
    for (int s = 0; s < 16; ++s) {
        const int srcq = plus ? ((nl + s) & 15) : ((nl + 16 - s) & 15);
        wfhp[s] = Wf[(64 + srcq) * 64 + j];
    }

    F8 B1h[4], B1l[4];
#pragma unroll
    for (int T = 0; T < 4; ++T) {
        float w[8];
#pragma unroll
        for (int e = 0; e < 8; ++e) {
            int k = quad * 8 + e;
            w[e] = (k < 20) ? W0[k * 64 + T * 16 + nl] : 0.f;
        }
        split_pack(w, B1h[T].u, B1l[T].u);
    }
    F8 B2h[4][2], B2l[4][2];
#pragma unroll
    for (int T = 0; T < 4; ++T)
#pragma unroll
        for (int KH = 0; KH < 2; ++KH) {
            float w[8];
#pragma unroll
            for (int e = 0; e < 8; ++e) {
                int k = KH * 32 + quad * 8 + e;
                w[e] = Wf[k * 64 + T * 16 + nl];
            }
            split_pack(w, B2h[T][KH].u, B2l[T][KH].u);
        }

    float b0v[4], bfv[4];
#pragma unroll
    for (int T = 0; T < 4; ++T) {
        b0v[T] = b0[T * 16 + nl];
        bfv[T] = bf[T * 16 + nl];
    }

    const float gmul  = (quad == 1) ? -2.f : -1.f;
    const float gbias = (quad == 2) ? 1.f : 0.f;
    const float amul  = (quad == 1) ? 2.f : 1.f;
    const float aadd  = (quad == 1) ? -1.f : 0.f;
    const bool  b0sel = (quad & 1) != 0;
    const bool  b1sel = (quad & 2) != 0;

    float c = 0.f, hh = 0.f;
    const float* xb = x + (size_t)b * (256 * 20);

#pragma unroll 1
    for (int ch = 0; ch < 16; ++ch) {
        const int t0 = ch * 16;
        const float* xrow = xb + (size_t)(t0 + nl) * 20;
        float xk[8];
#pragma unroll
        for (int e = 0; e < 8; ++e) {
            int k = quad * 8 + e;
            xk[e] = (k < 20) ? xrow[k] : 0.f;
        }
        F8 A1h, A1l;
        split_pack(xk, A1h.u, A1l.u);

        floatx4 acc1[4];
#pragma unroll
        for (int T = 0; T < 4; ++T) acc1[T] = (floatx4){b0v[T], b0v[T], b0v[T], b0v[T]};
#pragma unroll
        for (int T = 0; T < 4; ++T) {
            acc1[T] = __builtin_amdgcn_mfma_f32_16x16x32_bf16(A1h.v, B1h[T].v, acc1[T], 0, 0, 0);
            acc1[T] = __builtin_amdgcn_mfma_f32_16x16x32_bf16(A1l.v, B1h[T].v, acc1[T], 0, 0, 0);
            acc1[T] = __builtin_amdgcn_mfma_f32_16x16x32_bf16(A1h.v, B1l[T].v, acc1[T], 0, 0, 0);
        }
#pragma unroll
        for (int T = 0; T < 4; ++T)
#pragma unroll
            for (int reg = 0; reg < 4; ++reg)
                lds_xh[(quad * 4 + reg) * LDW + T * 16 + nl] = fmaxf(acc1[T][reg], 0.f);
        __builtin_amdgcn_wave_barrier();

        F8 A2h[2], A2l[2];
#pragma unroll
        for (int KH = 0; KH < 2; ++KH) {
            float xe[8];
#pragma unroll
            for (int e = 0; e < 8; ++e)
                xe[e] = lds_xh[nl * LDW + KH * 32 + quad * 8 + e];
            split_pack(xe, A2h[KH].u, A2l[KH].u);
        }

        floatx4 acc2[4];
#pragma unroll
        for (int T = 0; T < 4; ++T) acc2[T] = (floatx4){bfv[T], bfv[T], bfv[T], bfv[T]};
#pragma unroll
        for (int T = 0; T < 4; ++T)
#pragma unroll
            for (int KH = 0; KH < 2; ++KH) {
                acc2[T] = __builtin_amdgcn_mfma_f32_16x16x32_bf16(A2h[KH].v, B2h[T][KH].v, acc2[T], 0, 0, 0);
                acc2[T] = __builtin_amdgcn_mfma_f32_16x16x32_bf16(A2l[KH].v, B2h[T][KH].v, acc2[T], 0, 0, 0);
                acc2[T] = __builtin_amdgcn_mfma_f32_16x16x32_bf16(A2h[KH].v, B2l[T][KH].v, acc2[T], 0, 0, 0);
            }
#pragma unroll
        for (int T = 0; T < 4; ++T)
#pragma unroll
            for (int reg = 0; reg < 4; ++reg)
                lds_g[(quad * 4 + reg) * LDW + T * 16 + nl] = acc2[T][reg];
        __builtin_amdgcn_wave_barrier();

        float gcur = lds_g[j];
#pragma unroll
        for (int tau = 0; tau < 16; ++tau) {
            float gnext = lds_g[((tau < 15) ? (tau + 1) : 15) * LDW + j];
            float v0 = hh * wfhp[0];
            float v1 = ROT(hh, 1) * wfhp[1];
            float v2 = ROT(hh, 2) * wfhp[2];
            float v3 = ROT(hh, 3) * wfhp[3];
            v0 = fmaf(ROT(hh, 4),  wfhp[4],  v0);
            v1 = fmaf(ROT(hh, 5),  wfhp[5],  v1);
            v2 = fmaf(ROT(hh, 6),  wfhp[6],  v2);
            v3 = fmaf(ROT(hh, 7),  wfhp[7],  v3);
            v0 = fmaf(ROT(hh, 8),  wfhp[8],  v0);
            v1 = fmaf(ROT(hh, 9),  wfhp[9],  v1);
            v2 = fmaf(ROT(hh, 10), wfhp[10], v2);
            v3 = fmaf(ROT(hh, 11), wfhp[11], v3);
            v0 = fmaf(ROT(hh, 12), wfhp[12], v0);
            v1 = fmaf(ROT(hh, 13), wfhp[13], v1);
            v2 = fmaf(ROT(hh, 14), wfhp[14], v2);
            v3 = fmaf(ROT(hh, 15), wfhp[15], v3);
            float gated = gcur + ((v0 + v1) + (v2 + v3));

            float e = __expf(gmul * (gated + gbias));
            float y = __fdividef(1.f, 1.f + e);
            float a = fmaf(y, amul, aadd);

            float d1 = __shfl_xor(a, 16);
            float d2 = __shfl_xor(a, 32);
            float d3 = __shfl_xor(a, 48);
            float lo  = b0sel ? d1 : a;
            float hi  = b0sel ? d3 : d2;
            float lo1 = b0sel ? a  : d1;
            float hi1 = b0sel ? d2 : d3;
            float ai = b1sel ? hi  : lo;
            float ag = b1sel ? hi1 : lo1;
            float af = b1sel ? lo  : hi;
            float ao = b1sel ? lo1 : hi1;

            c  = fmaf(af, c, ai * ag);
            hh = ao * tanh_fast(c);
            gcur = gnext;
        }
    }

    if (j < 16) h_sh[j] = hh;
    __builtin_amdgcn_wave_barrier();

    {
        float u0 = bb[j], u1 = 0.f, u2 = 0.f, u3 = 0.f;
        const float* xr = &lds_xh[15 * LDW];
#pragma unroll
        for (int k4 = 0; k4 < 16; ++k4) {
            u0 = fmaf(xr[4 * k4 + 0], Wb[(4 * k4 + 0) * 64 + j], u0);
            u1 = fmaf(xr[4 * k4 + 1], Wb[(4 * k4 + 1) * 64 + j], u1);
            u2 = fmaf(xr[4 * k4 + 2], Wb[(4 * k4 + 2) * 64 + j], u2);
            u3 = fmaf(xr[4 * k4 + 3], Wb[(4 * k4 + 3) * 64 + j], u3);
        }
        float gated = (u0 + u1) + (u2 + u3);
        float e = __expf(gmul * gated);
        float y = __fdividef(1.f, 1.f + e);
        float a = fmaf(y, amul, aadd);
        float ai = __shfl(a, nl, 64);
        float ag = __shfl(a, nl + 16, 64);
        float ao = __shfl(a, nl + 48, 64);
        float cb = ai * ag;
        float hb = ao * tanh_fast(cb);
        __builtin_amdgcn_wave_barrier();
        if (j < 16) h_sh[16 + j] = hb;
        __builtin_amdgcn_wave_barrier();
    }

    {
        float u0 = b1[j], u1 = 0.f, u2 = 0.f, u3 = 0.f;
        const float4* hs = (const float4*)h_sh;
#pragma unroll
        for (int k4 = 0; k4 < 8; ++k4) {
            float4 v = hs[k4];
            u0 = fmaf(v.x, W1[(4 * k4 + 0) * 64 + j], u0);
            u1 = fmaf(v.y, W1[(4 * k4 + 1) * 64 + j], u1);
            u2 = fmaf(v.z, W1[(4 * k4 + 2) * 64 + j], u2);
            u3 = fmaf(v.w, W1[(4 * k4 + 3) * 64 + j], u3);
        }
        float l1 = fmaxf((u0 + u1) + (u2 + u3), 0.f);
        __builtin_amdgcn_wave_barrier();
        lds_g[j] = l1;
        __builtin_amdgcn_wave_barrier();

        if (j < 16) {
            float v0 = b2[j], v1 = 0.f, v2 = 0.f, v3 = 0.f;
            const float4* ls = (const float4*)lds_g;
#pragma unroll
            for (int k4 = 0; k4 < 16; ++k4) {
                float4 v = ls[k4];
                v0 = fmaf(v.x, W2[(4 * k4 + 0) * 16 + j], v0);
                v1 = fmaf(v.y, W2[(4 * k4 + 1) * 16 + j], v1);
                v2 = fmaf(v.z, W2[(4 * k4 + 2) * 16 + j], v2);
                v3 = fmaf(v.w, W2[(4 * k4 + 3) * 16 + j], v3);
            }
            h_sh[32 + j] = fmaxf((v0 + v1) + (v2 + v3), 0.f);
        }
        __builtin_amdgcn_wave_barrier();

        if (j < 2) {
            float o = b3[j];
#pragma unroll
            for (int k = 0; k < 16; ++k)
                o = fmaf(h_sh[32 + k], W3[k * 2 + j], o);
            out[b * 2 + j] = o;
        }
    }
}

extern "C" void kernel_launch(void* const* d_in, const int* in_sizes, int n_in,
                              void* d_out, int out_size, void* d_ws, size_t ws_size,
                              hipStream_t stream) {
    const float* x  = (const float*)d_in[0];
    const float* W0 = (const float*)d_in[1];
    const float* b0 = (const float*)d_in[2];
    const float* Wf = (const float*)d_in[3];
    const float* bf = (const float*)d_in[4];
    const float* Wb = (const float*)d_in[5];
    const float* bb = (const float*)d_in[6];
    const float* W1 = (const float*)d_in[7];
    const float* b1 = (const float*)d_in[8];
    const float* W2 = (const float*)d_in[9];
    const float* b2 = (const float*)d_in[10];
    const float* W3 = (const float*)d_in[11];
    const float* b3 = (const float*)d_in[12];
    float* outp = (float*)d_out;

    const size_t need = (size_t)4096 * 256 * 64 * sizeof(float);  // 268 MB
    if (ws_size >= need) {
        float* gpre = (float*)d_ws;
        hipLaunchKernelGGL(gpre_gemm, dim3(1024), dim3(256), 0, stream,
                           x, W0, b0, Wf, bf, gpre);
        hipLaunchKernelGGL(lstm_scan, dim3(1024), dim3(256), 0, stream,
                           gpre, x, W0, b0, Wf, Wb, bb, W1, b1, W2, b2, W3, b3, outp);
    } else {
        hipLaunchKernelGGL(bilstm_fused_r4, dim3(4096), dim3(64), 0, stream,
                           x, W0, b0, Wf, bf, Wb, bb, W1, b1, W2, b2, W3, b3, outp);
    }
}

// Round 8
// 288.581 us; speedup vs baseline: 2.1745x; 1.2395x over previous
//
#include <hip/hip_runtime.h>

// BiLSTM for MI355X (gfx950) — round 8.
//  K1 gpre_gemm: R7 structure (streaming 16 tiles/wave, split-bf16 MFMA, verified)
//     but gpre now stored as f16 PAIRS (steps 2t,2t+1 packed per dword, RNE) ->
//     write traffic 268 -> 134 MB.
//  K2 lstm_scan: R5/R7 structure with three surgical edits:
//     (a) __fdividef -> __builtin_amdgcn_rcpf (avoids IEEE div expansion, ~10 inst each)
//     (b) butterfly (3 shfl_xor + 8 cndmask) -> 4 pre-addressed ds_bpermute
//     (c) f16-pair gpre loads (1 dword / 2 steps), parity double-buffered blocks.
//  Fallback: unchanged R4 fused kernel if ws_size < 140 MB.

typedef __attribute__((ext_vector_type(8))) short short8;
typedef __attribute__((ext_vector_type(4))) float floatx4;

union F8 { uint32_t u[4]; short8 v; };
union H2 { uint32_t u; _Float16 h[2]; };

#define LDW  66  // fallback-kernel LDS stride (R4 layout, unchanged)
#define LDW2 68  // K1 stride: keeps all b128 LDS accesses 16B-aligned; 68%32=4

__device__ __forceinline__ float tanh_fast(float x) {
    float e = __expf(-2.f * x);
    return __fdividef(2.f, 1.f + e) - 1.f;
}

// rotate v right by S within each row of 16 lanes (DPP row_ror:S)
#define ROT(v, S) __int_as_float(__builtin_amdgcn_mov_dpp(__float_as_int(v), 0x120 | (S), 0xf, 0xf, false))

// split f[0..7] (fp32) into truncated-bf16 hi and residual-bf16 lo fragments (R4-verified)
__device__ __forceinline__ void split_pack(const float* f, uint32_t* hi, uint32_t* lo) {
#pragma unroll
    for (int i = 0; i < 4; ++i) {
        uint32_t u0 = __float_as_uint(f[2 * i]), u1 = __float_as_uint(f[2 * i + 1]);
        hi[i] = (u0 >> 16) | (u1 & 0xFFFF0000u);
        float r0 = f[2 * i]     - __uint_as_float(u0 & 0xFFFF0000u);
        float r1 = f[2 * i + 1] - __uint_as_float(u1 & 0xFFFF0000u);
        uint32_t v0 = __float_as_uint(r0), v1 = __float_as_uint(r1);
        lo[i] = (v0 >> 16) | (v1 & 0xFFFF0000u);
    }
}

// ===================== K1: streaming gpre GEMM (f16-pair output) =====================
// grid 1024 x 256. wave_id = blockIdx*4+wv handles rows [wave_id*256, +256) in 16 tiles.
__global__ __launch_bounds__(256, 2)
void gpre_gemm(const float* __restrict__ x,
               const float* __restrict__ W0, const float* __restrict__ b0,
               const float* __restrict__ Wf, const float* __restrict__ bf,
               uint32_t* __restrict__ gph)
{
    __shared__ __align__(16) float tA[4][16 * LDW2];  // xh transpose (wave-private)
    __shared__ __align__(16) float tB[4][16 * LDW2];  // gpre transpose (wave-private)

    const int tid  = threadIdx.x;
    const int wv   = tid >> 6;
    const int j    = tid & 63;
    const int nl   = j & 15;
    const int quad = j >> 4;

    // ---- B fragments (gathered once, used for 16 tiles)
    F8 B1h[4], B1l[4];
#pragma unroll
    for (int T = 0; T < 4; ++T) {
        float w[8];
#pragma unroll
        for (int e = 0; e < 8; ++e) {
            int k = quad * 8 + e;
            w[e] = (k < 20) ? W0[k * 64 + T * 16 + nl] : 0.f;
        }
        split_pack(w, B1h[T].u, B1l[T].u);
    }
    F8 B2h[4][2], B2l[4][2];
#pragma unroll
    for (int T = 0; T < 4; ++T)
#pragma unroll
        for (int KH = 0; KH < 2; ++KH) {
            float w[8];
#pragma unroll
            for (int e = 0; e < 8; ++e) {
                int k = KH * 32 + quad * 8 + e;
                w[e] = Wf[k * 64 + T * 16 + nl];
            }
            split_pack(w, B2h[T][KH].u, B2l[T][KH].u);
        }

    float b0v[4], bfv[4];
#pragma unroll
    for (int T = 0; T < 4; ++T) {
        b0v[T] = b0[T * 16 + nl];
        bfv[T] = bf[T * 16 + nl] + ((T == 2) ? 1.f : 0.f);   // fold haiku forget +1
    }

    const size_t base = (size_t)(blockIdx.x * 4 + wv) * 256;

    // ---- x prefetch (1 tile deep). Lane (quad,nl) needs x[r+nl][quad*8 .. +7].
    float4 xp0, xp1;
    {
        const float* xr = x + (base + nl) * 20;
        if (quad < 2) {
            xp0 = *(const float4*)(xr + quad * 8);
            xp1 = *(const float4*)(xr + quad * 8 + 4);
        } else if (quad == 2) {
            xp0 = *(const float4*)(xr + 16);
            xp1 = (float4){0.f, 0.f, 0.f, 0.f};
        } else {
            xp0 = (float4){0.f, 0.f, 0.f, 0.f};
            xp1 = (float4){0.f, 0.f, 0.f, 0.f};
        }
    }

#pragma unroll 1
    for (int tile = 0; tile < 16; ++tile) {
        float xk[8] = {xp0.x, xp0.y, xp0.z, xp0.w, xp1.x, xp1.y, xp1.z, xp1.w};

        // prefetch next tile's x
        {
            int tn = (tile < 15) ? (tile + 1) : 15;
            const float* xr = x + (base + tn * 16 + nl) * 20;
            if (quad < 2) {
                xp0 = *(const float4*)(xr + quad * 8);
                xp1 = *(const float4*)(xr + quad * 8 + 4);
            } else if (quad == 2) {
                xp0 = *(const float4*)(xr + 16);
            }
        }

        F8 A1h, A1l;
        split_pack(xk, A1h.u, A1l.u);

        floatx4 acc1[4];
#pragma unroll
        for (int T = 0; T < 4; ++T) acc1[T] = (floatx4){b0v[T], b0v[T], b0v[T], b0v[T]};
#pragma unroll
        for (int T = 0; T < 4; ++T) {
            acc1[T] = __builtin_amdgcn_mfma_f32_16x16x32_bf16(A1h.v, B1h[T].v, acc1[T], 0, 0, 0);
            acc1[T] = __builtin_amdgcn_mfma_f32_16x16x32_bf16(A1l.v, B1h[T].v, acc1[T], 0, 0, 0);
            acc1[T] = __builtin_amdgcn_mfma_f32_16x16x32_bf16(A1h.v, B1l[T].v, acc1[T], 0, 0, 0);
        }

        // relu + transpose (C-layout -> [tau][e])
#pragma unroll
        for (int T = 0; T < 4; ++T)
#pragma unroll
            for (int reg = 0; reg < 4; ++reg)
                tA[wv][(quad * 4 + reg) * LDW2 + T * 16 + nl] = fmaxf(acc1[T][reg], 0.f);
        __builtin_amdgcn_wave_barrier();

        F8 A2h[2], A2l[2];
#pragma unroll
        for (int KH = 0; KH < 2; ++KH) {
            float xe[8];
#pragma unroll
            for (int e = 0; e < 8; ++e)
                xe[e] = tA[wv][nl * LDW2 + KH * 32 + quad * 8 + e];
            split_pack(xe, A2h[KH].u, A2l[KH].u);
        }

        floatx4 acc2[4];
#pragma unroll
        for (int T = 0; T < 4; ++T) acc2[T] = (floatx4){bfv[T], bfv[T], bfv[T], bfv[T]};
#pragma unroll
        for (int T = 0; T < 4; ++T)
#pragma unroll
            for (int KH = 0; KH < 2; ++KH) {
                acc2[T] = __builtin_amdgcn_mfma_f32_16x16x32_bf16(A2h[KH].v, B2h[T][KH].v, acc2[T], 0, 0, 0);
                acc2[T] = __builtin_amdgcn_mfma_f32_16x16x32_bf16(A2l[KH].v, B2h[T][KH].v, acc2[T], 0, 0, 0);
                acc2[T] = __builtin_amdgcn_mfma_f32_16x16x32_bf16(A2h[KH].v, B2l[T][KH].v, acc2[T], 0, 0, 0);
            }

        // gpre transpose -> [tau][gate] rows in LDS
#pragma unroll
        for (int T = 0; T < 4; ++T)
#pragma unroll
            for (int reg = 0; reg < 4; ++reg)
                tB[wv][(quad * 4 + reg) * LDW2 + T * 16 + nl] = acc2[T][reg];
        __builtin_amdgcn_wave_barrier();

        // pack step-pairs (2tp, 2tp+1) to f16x2 (RNE), coalesced dword stores
        uint32_t* gp = gph + ((base >> 1) + tile * 8) * 64;
#pragma unroll
        for (int tp = 0; tp < 8; ++tp) {
            float a0 = tB[wv][(2 * tp) * LDW2 + j];
            float a1 = tB[wv][(2 * tp + 1) * LDW2 + j];
            H2 pk;
            pk.h[0] = (_Float16)a0;   // v_cvt_f16_f32 (RNE)
            pk.h[1] = (_Float16)a1;
            gp[tp * 64 + j] = pk.u;
        }
        __builtin_amdgcn_wave_barrier();   // protect tA/tB reuse next tile
    }
}

// ===================== K2: serial scan + epilogue =====================
// R5/R7 structure; edits: rcp instead of divide, ds_bpermute gather, f16-pair gpre.
__global__ __launch_bounds__(256, 4)
void lstm_scan(const uint32_t* __restrict__ gph,
               const float* __restrict__ x,
               const float* __restrict__ W0, const float* __restrict__ b0,
               const float* __restrict__ Wf,
               const float* __restrict__ Wb, const float* __restrict__ bb,
               const float* __restrict__ W1, const float* __restrict__ b1,
               const float* __restrict__ W2, const float* __restrict__ b2,
               const float* __restrict__ W3, const float* __restrict__ b3,
               float* __restrict__ out)
{
    __shared__ __align__(16) float xh_sh[4][64];
    __shared__ __align__(16) float h_sh[4][48];   // [0:16) hf, [16:32) hb, [32:48) l2

    const int wv   = threadIdx.x >> 6;
    const int j    = threadIdx.x & 63;
    const int b    = blockIdx.x * 4 + wv;
    const int nl   = j & 15;
    const int quad = j >> 4;

    int rot1 = __builtin_amdgcn_mov_dpp(j, 0x121, 0xf, 0xf, false);
    const bool plus = ((rot1 & 15) == ((nl + 1) & 15));

    float wfhp[16];
#pragma unroll
    for (int s = 0; s < 16; ++s) {
        const int srcq = plus ? ((nl + s) & 15) : ((nl + 16 - s) & 15);
        wfhp[s] = Wf[(64 + srcq) * 64 + j];
    }

    const float gmul  = (quad == 1) ? -2.f : -1.f;   // f-gate +1 folded in gpre
    const float amul  = (quad == 1) ? 2.f : 1.f;
    const float aadd  = (quad == 1) ? -1.f : 0.f;

    // bpermute byte-addresses for gathering i/g/f/o of unit nl (hoisted)
    const int adr_i = 4 * nl;
    const int adr_g = 4 * nl + 64;
    const int adr_f = 4 * nl + 128;
    const int adr_o = 4 * nl + 192;

    float c = 0.f, hh = 0.f;
    const uint32_t* gb = gph + (size_t)b * (128 * 64);

    // one LSTM step given fp32 gate pre-activation G (R2..R7-verified math,
    // divide->rcp, butterfly->bpermute)
#define STEPG(G)                                                          \
    {                                                                     \
        float v0 = fmaf(hh, wfhp[0], (G));                                \
        float v1 = ROT(hh, 1) * wfhp[1];                                  \
        float v2 = ROT(hh, 2) * wfhp[2];                                  \
        float v3 = ROT(hh, 3) * wfhp[3];                                  \
        v0 = fmaf(ROT(hh, 4),  wfhp[4],  v0);                             \
        v1 = fmaf(ROT(hh, 5),  wfhp[5],  v1);                             \
        v2 = fmaf(ROT(hh, 6),  wfhp[6],  v2);                             \
        v3 = fmaf(ROT(hh, 7),  wfhp[7],  v3);                             \
        v0 = fmaf(ROT(hh, 8),  wfhp[8],  v0);                             \
        v1 = fmaf(ROT(hh, 9),  wfhp[9],  v1);                             \
        v2 = fmaf(ROT(hh, 10), wfhp[10], v2);                             \
        v3 = fmaf(ROT(hh, 11), wfhp[11], v3);                             \
        v0 = fmaf(ROT(hh, 12), wfhp[12], v0);                             \
        v1 = fmaf(ROT(hh, 13), wfhp[13], v1);                             \
        v2 = fmaf(ROT(hh, 14), wfhp[14], v2);                             \
        v3 = fmaf(ROT(hh, 15), wfhp[15], v3);                             \
        float gated = (v0 + v1) + (v2 + v3);                              \
        float e = __expf(gmul * gated);                                   \
        float y = __builtin_amdgcn_rcpf(1.f + e);                         \
        float a = fmaf(y, amul, aadd);                                    \
        int ab = __float_as_int(a);                                       \
        float ai = __int_as_float(__builtin_amdgcn_ds_bpermute(adr_i, ab)); \
        float ag = __int_as_float(__builtin_amdgcn_ds_bpermute(adr_g, ab)); \
        float af = __int_as_float(__builtin_amdgcn_ds_bpermute(adr_f, ab)); \
        float ao = __int_as_float(__builtin_amdgcn_ds_bpermute(adr_o, ab)); \
        c = fmaf(af, c, ai * ag);                                         \
        float e2 = __expf(-2.f * c);                                      \
        float th = fmaf(__builtin_amdgcn_rcpf(1.f + e2), 2.f, -1.f);      \
        hh = ao * th;                                                     \
    }

    // parity double-buffered blocks: 16 blocks x 8 dwords (= 16 steps each)
    uint32_t bufA[8], bufB[8];
#pragma unroll
    for (int i = 0; i < 8; ++i) bufA[i] = gb[i * 64 + j];
#pragma unroll
    for (int i = 0; i < 8; ++i) bufB[i] = gb[(8 + i) * 64 + j];

#pragma unroll 1
    for (int blk = 0; blk < 16; blk += 2) {
#pragma unroll
        for (int p = 0; p < 8; ++p) {
            H2 u; u.u = bufA[p];
            float g0 = (float)u.h[0];
            float g1 = (float)u.h[1];
            STEPG(g0)
            STEPG(g1)
        }
        {
            int nb = blk + 2; nb = (nb > 15) ? 15 : nb;   // uniform clamp
#pragma unroll
            for (int i = 0; i < 8; ++i) bufA[i] = gb[(nb * 8 + i) * 64 + j];
        }
#pragma unroll
        for (int p = 0; p < 8; ++p) {
            H2 u; u.u = bufB[p];
            float g0 = (float)u.h[0];
            float g1 = (float)u.h[1];
            STEPG(g0)
            STEPG(g1)
        }
        {
            int nb = blk + 3; nb = (nb > 15) ? 15 : nb;
#pragma unroll
            for (int i = 0; i < 8; ++i) bufB[i] = gb[(nb * 8 + i) * 64 + j];
        }
    }
#undef STEPG

    // epilogue: recompute xh[255] exactly from x (verbatim R7)
    {
        const float* xr = x + (size_t)b * (256 * 20) + 255 * 20;
        float s = b0[j];
#pragma unroll
        for (int k = 0; k < 20; ++k) s = fmaf(xr[k], W0[k * 64 + j], s);
        xh_sh[wv][j] = fmaxf(s, 0.f);
        if (j < 16) h_sh[wv][j] = hh;
    }
    __builtin_amdgcn_wave_barrier();

    // bwd LSTM single step from zero state (verbatim R7)
    {
        float u0 = bb[j], u1 = 0.f, u2 = 0.f, u3 = 0.f;
        const float* xr = xh_sh[wv];
#pragma unroll
        for (int k4 = 0; k4 < 16; ++k4) {
            u0 = fmaf(xr[4 * k4 + 0], Wb[(4 * k4 + 0) * 64 + j], u0);
            u1 = fmaf(xr[4 * k4 + 1], Wb[(4 * k4 + 1) * 64 + j], u1);
            u2 = fmaf(xr[4 * k4 + 2], Wb[(4 * k4 + 2) * 64 + j], u2);
            u3 = fmaf(xr[4 * k4 + 3], Wb[(4 * k4 + 3) * 64 + j], u3);
        }
        float gated = (u0 + u1) + (u2 + u3);
        float e = __expf(gmul * gated);
        float y = __fdividef(1.f, 1.f + e);
        float a = fmaf(y, amul, aadd);
        float ai = __shfl(a, nl, 64);
        float ag = __shfl(a, nl + 16, 64);
        float ao = __shfl(a, nl + 48, 64);
        float cb = ai * ag;
        float hb = ao * tanh_fast(cb);
        __builtin_amdgcn_wave_barrier();
        if (j < 16) h_sh[wv][16 + j] = hb;
        __builtin_amdgcn_wave_barrier();
    }

    // head MLP (verbatim R7)
    {
        float u0 = b1[j], u1 = 0.f, u2 = 0.f, u3 = 0.f;
        const float4* hs = (const float4*)h_sh[wv];
#pragma unroll
        for (int k4 = 0; k4 < 8; ++k4) {
            float4 v = hs[k4];
            u0 = fmaf(v.x, W1[(4 * k4 + 0) * 64 + j], u0);
            u1 = fmaf(v.y, W1[(4 * k4 + 1) * 64 + j], u1);
            u2 = fmaf(v.z, W1[(4 * k4 + 2) * 64 + j], u2);
            u3 = fmaf(v.w, W1[(4 * k4 + 3) * 64 + j], u3);
        }
        float l1 = fmaxf((u0 + u1) + (u2 + u3), 0.f);
        __builtin_amdgcn_wave_barrier();
        xh_sh[wv][j] = l1;
        __builtin_amdgcn_wave_barrier();

        if (j < 16) {
            float v0 = b2[j], v1 = 0.f, v2 = 0.f, v3 = 0.f;
            const float4* ls = (const float4*)xh_sh[wv];
#pragma unroll
            for (int k4 = 0; k4 < 16; ++k4) {
                float4 v = ls[k4];
                v0 = fmaf(v.x, W2[(4 * k4 + 0) * 16 + j], v0);
                v1 = fmaf(v.y, W2[(4 * k4 + 1) * 16 + j], v1);
                v2 = fmaf(v.z, W2[(4 * k4 + 2) * 16 + j], v2);
                v3 = fmaf(v.w, W2[(4 * k4 + 3) * 16 + j], v3);
            }
            h_sh[wv][32 + j] = fmaxf((v0 + v1) + (v2 + v3), 0.f);
        }
        __builtin_amdgcn_wave_barrier();

        if (j < 2) {
            float o = b3[j];
#pragma unroll
            for (int k = 0; k < 16; ++k)
                o = fmaf(h_sh[wv][32 + k], W3[k * 2 + j], o);
            out[b * 2 + j] = o;
        }
    }
}

// ===================== fallback: unchanged R4 fused kernel =====================
__global__ __launch_bounds__(64, 2)
void bilstm_fused_r4(const float* __restrict__ x,
                     const float* __restrict__ W0, const float* __restrict__ b0,
                     const float* __restrict__ Wf, const float* __restrict__ bf,
                     const float* __restrict__ Wb, const float* __restrict__ bb,
                     const float* __restrict__ W1, const float* __restrict__ b1,
                     const float* __restrict__ W2, const float* __restrict__ b2,
                     const float* __restrict__ W3, const float* __restrict__ b3,
                     float* __restrict__ out)
{
    __shared__ __align__(16) float lds_xh[16 * LDW];
    __shared__ __align__(16) float lds_g [16 * LDW];
    __shared__ __align__(16) float h_sh[48];

    const int j    = threadIdx.x;
    const int b    = blockIdx.x;
    const int nl   = j & 15;
    const int quad = j >> 4;

    int rot1 = __builtin_amdgcn_mov_dpp(j, 0x121, 0xf, 0xf, false);
    const bool plus = ((rot1 & 15) == ((nl + 1) & 15));

    float wfhp[16];
#pragma unroll
    for (int s = 0; s < 16; ++s) {
        const int srcq = plus ? ((nl + s) & 15) : ((nl + 16 - s) & 15);
        wfhp[s] = Wf[(64 + srcq) * 64 + j];
    }

    F8 B1h[4], B1l[4];
#pragma unroll
    for (int T = 0; T < 4; ++T) {
        float w[8];
#pragma unroll
        for (int e = 0; e < 8; ++e) {
            int k = quad * 8 + e;
            w[e] = (k < 20) ? W0[k * 64 + T * 16 + nl] : 0.f;
        }
        split_pack(w, B1h[T].u, B1l[T].u);
    }
    F8 B2h[4][2], B2l[4][2];
#pragma unroll
    for (int T = 0; T < 4; ++T)
#pragma unroll
        for (int KH = 0; KH < 2; ++KH) {
            float w[8];
#pragma unroll
            for (int e = 0; e < 8; ++e) {
                int k = KH * 32 + quad * 8 + e;
                w[e] = Wf[k * 64 + T * 16 + nl];
            }
            split_pack(w, B2h[T][KH].u, B2l[T][KH].u);
        }

    float b0v[4], bfv[4];
#pragma unroll
    for (int T = 0; T < 4; ++T) {
        b0v[T] = b0[T * 16 + nl];
        bfv[T] = bf[T * 16 + nl];
    }

    const float gmul  = (quad == 1) ? -2.f : -1.f;
    const float gbias = (quad == 2) ? 1.f : 0.f;
    const float amul  = (quad == 1) ? 2.f : 1.f;
    const float aadd  = (quad == 1) ? -1.f : 0.f;
    const bool  b0sel = (quad & 1) != 0;
    const bool  b1sel = (quad & 2) != 0;

    float c = 0.f, hh = 0.f;
    const float* xb = x + (size_t)b * (256 * 20);

#pragma unroll 1
    for (int ch = 0; ch < 16; ++ch) {
        const int t0 = ch * 16;
        const float* xrow = xb + (size_t)(t0 + nl) * 20;
        float xk[8];
#pragma unroll
        for (int e = 0; e < 8; ++e) {
            int k = quad * 8 + e;
            xk[e] = (k < 20) ? xrow[k] : 0.f;
        }
        F8 A1h, A1l;
        split_pack(xk, A1h.u, A1l.u);

        floatx4 acc1[4];
#pragma unroll
        for (int T = 0; T < 4; ++T) acc1[T] = (floatx4){b0v[T], b0v[T], b0v[T], b0v[T]};
#pragma unroll
        for (int T = 0; T < 4; ++T) {
            acc1[T] = __builtin_amdgcn_mfma_f32_16x16x32_bf16(A1h.v, B1h[T].v, acc1[T], 0, 0, 0);
            acc1[T] = __builtin_amdgcn_mfma_f32_16x16x32_bf16(A1l.v, B1h[T].v, acc1[T], 0, 0, 0);
            acc1[T] = __builtin_amdgcn_mfma_f32_16x16x32_bf16(A1h.v, B1l[T].v, acc1[T], 0, 0, 0);
        }
#pragma unroll
        for (int T = 0; T < 4; ++T)
#pragma unroll
            for (int reg = 0; reg < 4; ++reg)
                lds_xh[(quad * 4 + reg) * LDW + T * 16 + nl] = fmaxf(acc1[T][reg], 0.f);
        __builtin_amdgcn_wave_barrier();

        F8 A2h[2], A2l[2];
#pragma unroll
        for (int KH = 0; KH < 2; ++KH) {
            float xe[8];
#pragma unroll
            for (int e = 0; e < 8; ++e)
                xe[e] = lds_xh[nl * LDW + KH * 32 + quad * 8 + e];
            split_pack(xe, A2h[KH].u, A2l[KH].u);
        }

        floatx4 acc2[4];
#pragma unroll
        for (int T = 0; T < 4; ++T) acc2[T] = (floatx4){bfv[T], bfv[T], bfv[T], bfv[T]};
#pragma unroll
        for (int T = 0; T < 4; ++T)
#pragma unroll
            for (int KH = 0; KH < 2; ++KH) {
                acc2[T] = __builtin_amdgcn_mfma_f32_16x16x32_bf16(A2h[KH].v, B2h[T][KH].v, acc2[T], 0, 0, 0);
                acc2[T] = __builtin_amdgcn_mfma_f32_16x16x32_bf16(A2l[KH].v, B2h[T][KH].v, acc2[T], 0, 0, 0);
                acc2[T] = __builtin_amdgcn_mfma_f32_16x16x32_bf16(A2h[KH].v, B2l[T][KH].v, acc2[T], 0, 0, 0);
            }
#pragma unroll
        for (int T = 0; T < 4; ++T)
#pragma unroll
            for (int reg = 0; reg < 4; ++reg)
                lds_g[(quad * 4 + reg) * LDW + T * 16 + nl] = acc2[T][reg];
        __builtin_amdgcn_wave_barrier();

        float gcur = lds_g[j];
#pragma unroll
        for (int tau = 0; tau < 16; ++tau) {
            float gnext = lds_g[((tau < 15) ? (tau + 1) : 15) * LDW + j];
            float v0 = hh * wfhp[0];
            float v1 = ROT(hh, 1) * wfhp[1];
            float v2 = ROT(hh, 2) * wfhp[2];
            float v3 = ROT(hh, 3) * wfhp[3];
            v0 = fmaf(ROT(hh, 4),  wfhp[4],  v0);
            v1 = fmaf(ROT(hh, 5),  wfhp[5],  v1);
            v2 = fmaf(ROT(hh, 6),  wfhp[6],  v2);
            v3 = fmaf(ROT(hh, 7),  wfhp[7],  v3);
            v0 = fmaf(ROT(hh, 8),  wfhp[8],  v0);
            v1 = fmaf(ROT(hh, 9),  wfhp[9],  v1);
            v2 = fmaf(ROT(hh, 10), wfhp[10], v2);
            v3 = fmaf(ROT(hh, 11), wfhp[11], v3);
            v0 = fmaf(ROT(hh, 12), wfhp[12], v0);
            v1 = fmaf(ROT(hh, 13), wfhp[13], v1);
            v2 = fmaf(ROT(hh, 14), wfhp[14], v2);
            v3 = fmaf(ROT(hh, 15), wfhp[15], v3);
            float gated = gcur + ((v0 + v1) + (v2 + v3));

            float e = __expf(gmul * (gated + gbias));
            float y = __fdividef(1.f, 1.f + e);
            float a = fmaf(y, amul, aadd);

            float d1 = __shfl_xor(a, 16);
            float d2 = __shfl_xor(a, 32);
            float d3 = __shfl_xor(a, 48);
            float lo  = b0sel ? d1 : a;
            float hi  = b0sel ? d3 : d2;
            float lo1 = b0sel ? a  : d1;
            float hi1 = b0sel ? d2 : d3;
            float ai = b1sel ? hi  : lo;
            float ag = b1sel ? hi1 : lo1;
            float af = b1sel ? lo  : hi;
            float ao = b1sel ? lo1 : hi1;

            c  = fmaf(af, c, ai * ag);
            hh = ao * tanh_fast(c);
            gcur = gnext;
        }
    }

    if (j < 16) h_sh[j] = hh;
    __builtin_amdgcn_wave_barrier();

    {
        float u0 = bb[j], u1 = 0.f, u2 = 0.f, u3 = 0.f;
        const float* xr = &lds_xh[15 * LDW];
#pragma unroll
        for (int k4 = 0; k4 < 16; ++k4) {
            u0 = fmaf(xr[4 * k4 + 0], Wb[(4 * k4 + 0) * 64 + j], u0);
            u1 = fmaf(xr[4 * k4 + 1], Wb[(4 * k4 + 1) * 64 + j], u1);
            u2 = fmaf(xr[4 * k4 + 2], Wb[(4 * k4 + 2) * 64 + j], u2);
            u3 = fmaf(xr[4 * k4 + 3], Wb[(4 * k4 + 3) * 64 + j], u3);
        }
        float gated = (u0 + u1) + (u2 + u3);
        float e = __expf(gmul * gated);
        float y = __fdividef(1.f, 1.f + e);
        float a = fmaf(y, amul, aadd);
        float ai = __shfl(a, nl, 64);
        float ag = __shfl(a, nl + 16, 64);
        float ao = __shfl(a, nl + 48, 64);
        float cb = ai * ag;
        float hb = ao * tanh_fast(cb);
        __builtin_amdgcn_wave_barrier();
        if (j < 16) h_sh[16 + j] = hb;
        __builtin_amdgcn_wave_barrier();
    }

    {
        float u0 = b1[j], u1 = 0.f, u2 = 0.f, u3 = 0.f;
        const float4* hs = (const float4*)h_sh;
#pragma unroll
        for (int k4 = 0; k4 < 8; ++k4) {
            float4 v = hs[k4];
            u0 = fmaf(v.x, W1[(4 * k4 + 0) * 64 + j], u0);
            u1 = fmaf(v.y, W1[(4 * k4 + 1) * 64 + j], u1);
            u2 = fmaf(v.z, W1[(4 * k4 + 2) * 64 + j], u2);
            u3 = fmaf(v.w, W1[(4 * k4 + 3) * 64 + j], u3);
        }
        float l1 = fmaxf((u0 + u1) + (u2 + u3), 0.f);
        __builtin_amdgcn_wave_barrier();
        lds_g[j] = l1;
        __builtin_amdgcn_wave_barrier();

        if (j < 16) {
            float v0 = b2[j], v1 = 0.f, v2 = 0.f, v3 = 0.f;
            const float4* ls = (const float4*)lds_g;
#pragma unroll
            for (int k4 = 0; k4 < 16; ++k4) {
                float4 v = ls[k4];
                v0 = fmaf(v.x, W2[(4 * k4 + 0) * 16 + j], v0);
                v1 = fmaf(v.y, W2[(4 * k4 + 1) * 16 + j], v1);
                v2 = fmaf(v.z, W2[(4 * k4 + 2) * 16 + j], v2);
                v3 = fmaf(v.w, W2[(4 * k4 + 3) * 16 + j], v3);
            }
            h_sh[32 + j] = fmaxf((v0 + v1) + (v2 + v3), 0.f);
        }
        __builtin_amdgcn_wave_barrier();

        if (j < 2) {
            float o = b3[j];
#pragma unroll
            for (int k = 0; k < 16; ++k)
                o = fmaf(h_sh[32 + k], W3[k * 2 + j], o);
            out[b * 2 + j] = o;
        }
    }
}

extern "C" void kernel_launch(void* const* d_in, const int* in_sizes, int n_in,
                              void* d_out, int out_size, void* d_ws, size_t ws_size,
                              hipStream_t stream) {
    const float* x  = (const float*)d_in[0];
    const float* W0 = (const float*)d_in[1];
    const float* b0 = (const float*)d_in[2];
    const float* Wf = (const float*)d_in[3];
    const float* bf = (const float*)d_in[4];
    const float* Wb = (const float*)d_in[5];
    const float* bb = (const float*)d_in[6];
    const float* W1 = (const float*)d_in[7];
    const float* b1 = (const float*)d_in[8];
    const float* W2 = (const float*)d_in[9];
    const float* b2 = (const float*)d_in[10];
    const float* W3 = (const float*)d_in[11];
    const float* b3 = (const float*)d_in[12];
    float* outp = (float*)d_out;

    const size_t need = (size_t)4096 * 128 * 64 * sizeof(uint32_t);  // 134 MB (f16 pairs)
    if (ws_size >= need) {
        uint32_t* gph = (uint32_t*)d_ws;
        hipLaunchKernelGGL(gpre_gemm, dim3(1024), dim3(256), 0, stream,
                           x, W0, b0, Wf, bf, gph);
        hipLaunchKernelGGL(lstm_scan, dim3(1024), dim3(256), 0, stream,
                           gph, x, W0, b0, Wf, Wb, bb, W1, b1, W2, b2, W3, b3, outp);
    } else {
        hipLaunchKernelGGL(bilstm_fused_r4, dim3(4096), dim3(64), 0, stream,
                           x, W0, b0, Wf, bf, Wb, bb, W1, b1, W2, b2, W3, b3, outp);
    }
}